// Round 14
// baseline (925.740 us; speedup 1.0000x reference)
//
#include <hip/hip_runtime.h>
#include <math.h>

// TiSASRec forward on MI355X — round 13:
//  - R12 post-mortem: cooperative launch silently failed (output stayed
//    zero => absmax ~ max|ref|). Replaced with a PERSISTENT regular-launch
//    megakernel + software grid barrier (atomics + threadfence), grid sized
//    by hipOccupancyMaxActiveBlocksPerMultiprocessor (deadlock-safe).
//  - Phase bodies are R9-exact (best measured: 183us total, attn 47.6us).
//  - Fallback: if occupancy query fails -> R9 6-launch path.
#define BB 32
#define LLEN 200
#define DD 64
#define HH 2
#define BLD (BB * LLEN * DD)
#define TSPAN1 366   // TIME_SPAN+1
#define NUNITS 1600

struct Params {
    const int *log_ids, *log_times, *pos_ids, *neg_ids;
    const float *item_emb, *posK, *posV, *tK_emb, *tV_emb;
    const float *ln1_g, *ln1_b, *Wq, *bq, *Wk, *bk, *Wv, *bv;
    const float *ln2_g, *ln2_b, *W1, *b1, *W2, *b2, *lnf_g, *lnf_b;
    float *q, *Qb, *Kb, *Vb, *att, *wt, *tKT, *Qt, *out;
    int *cnt, *gen;
    int nblk;
};

struct RowS { float qs[4][DD], xs[4][DD], hs[4][DD], Qsh[4][DD]; };
struct AttnS {
    int t_s[LLEN];
    float sc[4][HH][LLEN];
    unsigned short tm[4][LLEN];
    float qt[4][2 * TSPAN1];
};

__device__ inline float waveSum(float v) {
#pragma unroll
    for (int off = 32; off > 0; off >>= 1) v += __shfl_xor(v, off);
    return v;
}
__device__ inline float halfSum(float v) {
    v += __shfl_xor(v, 1);
    v += __shfl_xor(v, 2);
    v += __shfl_xor(v, 4);
    v += __shfl_xor(v, 8);
    v += __shfl_xor(v, 16);
    return v;
}
__device__ inline float halfMax(float v) {
    v = fmaxf(v, __shfl_xor(v, 1));
    v = fmaxf(v, __shfl_xor(v, 2));
    v = fmaxf(v, __shfl_xor(v, 4));
    v = fmaxf(v, __shfl_xor(v, 8));
    v = fmaxf(v, __shfl_xor(v, 16));
    return v;
}

// software grid barrier: safe because grid <= co-resident capacity
// (grid sized from hipOccupancyMaxActiveBlocksPerMultiprocessor).
__device__ inline void gridBarrier(int* cnt, int* gen, int nblk) {
    __syncthreads();
    if (threadIdx.x == 0) {
        __threadfence();                       // release prior writes
        int g = atomicAdd(gen, 0);
        if (atomicAdd(cnt, 1) == nblk - 1) {
            __threadfence();
            atomicExch(cnt, 0);
            __threadfence();
            atomicAdd(gen, 1);
        } else {
            while (atomicAdd(gen, 0) == g) __builtin_amdgcn_s_sleep(2);
        }
        __threadfence();                       // acquire
    }
    __syncthreads();
}

// ---- phase bodies (R9-exact math) ----

__device__ void phaseT(const Params& p, int m) {
    int tid = threadIdx.x;
    if (m < 10) {
        const float* src;
        switch (m % 5) {
            case 0: src = p.Wq; break;
            case 1: src = p.Wk; break;
            case 2: src = p.Wv; break;
            case 3: src = p.W1; break;
            default: src = p.W2; break;
        }
        src += (m / 5) * DD * DD;
        float* dst = p.wt + m * DD * DD;
        for (int e = tid; e < DD * DD; e += 256) {
            int d = e >> 6, j = e & 63;
            dst[j * DD + d] = src[e];
        }
    } else {
        for (int e = tid; e < TSPAN1 * DD; e += 256) {
            int t = e >> 6, d = e & 63;
            p.tKT[d * TSPAN1 + t] = p.tK_emb[e];
        }
    }
}

__device__ void qt_tail(const float (*Qsh)[DD], const float* __restrict__ tKT,
                        float* __restrict__ Qt_g, int base) {
    int tid = threadIdx.x;
    for (int t = tid; t < TSPAN1; t += 256) {
        const float* tk = tKT + t;
        float a0 = 0, a1 = 0, a2 = 0, a3 = 0;
#pragma unroll 8
        for (int d = 0; d < 32; ++d) {
            float v = tk[d * TSPAN1];
            a0 = fmaf(v, Qsh[0][d], a0);
            a1 = fmaf(v, Qsh[1][d], a1);
            a2 = fmaf(v, Qsh[2][d], a2);
            a3 = fmaf(v, Qsh[3][d], a3);
        }
        Qt_g[(size_t)(base + 0) * (2 * TSPAN1) + t] = a0;
        Qt_g[(size_t)(base + 1) * (2 * TSPAN1) + t] = a1;
        Qt_g[(size_t)(base + 2) * (2 * TSPAN1) + t] = a2;
        Qt_g[(size_t)(base + 3) * (2 * TSPAN1) + t] = a3;
        float b0 = 0, b1 = 0, b2 = 0, b3 = 0;
#pragma unroll 8
        for (int d = 32; d < 64; ++d) {
            float v = tk[d * TSPAN1];
            b0 = fmaf(v, Qsh[0][d], b0);
            b1 = fmaf(v, Qsh[1][d], b1);
            b2 = fmaf(v, Qsh[2][d], b2);
            b3 = fmaf(v, Qsh[3][d], b3);
        }
        Qt_g[(size_t)(base + 0) * (2 * TSPAN1) + TSPAN1 + t] = b0;
        Qt_g[(size_t)(base + 1) * (2 * TSPAN1) + TSPAN1 + t] = b1;
        Qt_g[(size_t)(base + 2) * (2 * TSPAN1) + TSPAN1 + t] = b2;
        Qt_g[(size_t)(base + 3) * (2 * TSPAN1) + TSPAN1 + t] = b3;
    }
}

__device__ void phaseA(RowS& sm, const Params& p, int u) {
    int tid = threadIdx.x, wid = tid >> 6, d = tid & 63;
    int row = u * 4 + wid, l = row % LLEN;
    int id = p.log_ids[row];
    float xv = (id == 0) ? 0.0f : p.item_emb[(size_t)id * DD + d] * 8.0f;
    sm.xs[wid][d] = xv;
    float m = waveSum(xv) * (1.0f / 64.0f);
    float c = xv - m;
    float var = waveSum(c * c) * (1.0f / 64.0f);
    float qv = (c / sqrtf(var + 1e-8f)) * p.ln1_g[d] + p.ln1_b[d];
    sm.qs[wid][d] = qv;
    p.q[(size_t)row * DD + d] = qv;
    const float* WqT = p.wt;
    const float* WkT = p.wt + DD * DD;
    const float* WvT = p.wt + 2 * DD * DD;
    float aq = p.bq[d], ak = p.bk[d], av = p.bv[d];
#pragma unroll 8
    for (int j = 0; j < DD; ++j) {
        aq = fmaf(sm.qs[wid][j], WqT[j * DD + d], aq);
        ak = fmaf(sm.xs[wid][j], WkT[j * DD + d], ak);
        av = fmaf(sm.xs[wid][j], WvT[j * DD + d], av);
    }
    p.Qb[(size_t)row * DD + d] = aq;
    p.Kb[(size_t)row * DD + d] = ak + p.posK[l * DD + d];
    p.Vb[(size_t)row * DD + d] = av + p.posV[l * DD + d];
    sm.Qsh[wid][d] = aq;
    __syncthreads();
    qt_tail(sm.Qsh, p.tKT, p.Qt, u * 4);
    __syncthreads();
}

__device__ void phaseAttn(AttnS& sm, const Params& p, int u) {
    int tid = threadIdx.x;
    int wid = tid >> 6;
    int lane = tid & 63;
    int bi = u / 50;
    int i = u % 50;
    int qi = (wid == 0) ? i : (wid == 1) ? (99 - i) : (wid == 2) ? (100 + i) : (199 - i);
    int row = bi * LLEN + qi;
    int len = qi + 1;

    if (tid < LLEN) sm.t_s[tid] = p.log_times[bi * LLEN + tid];
    __syncthreads();

    const float* qtrow_g = p.Qt + (size_t)row * (2 * TSPAN1);
    for (int e = lane; e < 2 * TSPAN1; e += 64) sm.qt[wid][e] = qtrow_g[e];

    int tq = sm.t_s[qi];
    for (int k = lane; k < len; k += 64) {
        int dt = tq - sm.t_s[k];
        if (dt < 0) dt = -dt;
        float dtf = fminf((float)dt * (1.0f / 86400.0f), 365.0f);
        sm.tm[wid][k] = (unsigned short)(int)dtf;
    }

    int h = lane >> 5;
    int l5 = lane & 31;
    int cch = l5 >> 2;
    int jo = l5 & 3;
    float4 qv = ((const float4*)(p.Qb + (size_t)row * DD))[h * 8 + cch];
    const float4* K4 = (const float4*)(p.Kb + (size_t)bi * LLEN * DD);
    const float scale = 0.17677669529663687f;  // 1/sqrt(32)

    for (int k0 = 0; k0 < len; k0 += 4) {
        int k = k0 + jo;
        int kc = (k < len) ? k : (len - 1);
        int bucket = sm.tm[wid][kc];
        float4 kv = K4[kc * 16 + h * 8 + cch];
        float pd = qv.x * kv.x + qv.y * kv.y + qv.z * kv.z + qv.w * kv.w;
        pd += __shfl_xor(pd, 4);
        pd += __shfl_xor(pd, 8);
        pd += __shfl_xor(pd, 16);
        float s = (pd + sm.qt[wid][h * TSPAN1 + bucket]) * scale;
        if (cch == 0 && k < len) sm.sc[wid][h][k] = s;
    }

    {
        float m = -INFINITY;
        for (int k = l5; k < len; k += 32) m = fmaxf(m, sm.sc[wid][h][k]);
        m = halfMax(m);
        float s = 0.0f;
        for (int k = l5; k < len; k += 32) {
            float e = expf(sm.sc[wid][h][k] - m);
            sm.sc[wid][h][k] = e;
            s += e;
        }
        s = halfSum(s);
        float inv = 1.0f / s;
        for (int k = l5; k < len; k += 32) sm.sc[wid][h][k] *= inv;
    }

    const float* Vb2 = p.Vb + (size_t)bi * LLEN * DD + lane;
    const float* tVl = p.tV_emb + lane;
    float acc0 = 0, acc1 = 0, acc2 = 0, acc3 = 0;
    int k = 0;
    for (; k + 4 <= len; k += 4) {
        int b0 = sm.tm[wid][k + 0];
        int b1 = sm.tm[wid][k + 1];
        int b2 = sm.tm[wid][k + 2];
        int b3 = sm.tm[wid][k + 3];
        float a0 = sm.sc[wid][h][k + 0];
        float a1 = sm.sc[wid][h][k + 1];
        float a2 = sm.sc[wid][h][k + 2];
        float a3 = sm.sc[wid][h][k + 3];
        acc0 = fmaf(a0, Vb2[(k + 0) * DD] + tVl[b0 * DD], acc0);
        acc1 = fmaf(a1, Vb2[(k + 1) * DD] + tVl[b1 * DD], acc1);
        acc2 = fmaf(a2, Vb2[(k + 2) * DD] + tVl[b2 * DD], acc2);
        acc3 = fmaf(a3, Vb2[(k + 3) * DD] + tVl[b3 * DD], acc3);
    }
    for (; k < len; ++k) {
        int b0 = sm.tm[wid][k];
        acc0 = fmaf(sm.sc[wid][h][k], Vb2[k * DD] + tVl[b0 * DD], acc0);
    }
    p.att[(size_t)row * DD + lane] = (acc0 + acc1) + (acc2 + acc3);
    __syncthreads();
}

__device__ void phaseC(RowS& sm, const Params& p, int u) {
    int tid = threadIdx.x, wid = tid >> 6, d = tid & 63;
    int row = u * 4 + wid, l = row % LLEN;
    float v = p.q[(size_t)row * DD + d] + p.att[(size_t)row * DD + d];
    float m = waveSum(v) * (1.0f / 64.0f);
    float c = v - m;
    float var = waveSum(c * c) * (1.0f / 64.0f);
    float xv = (c / sqrtf(var + 1e-8f)) * p.ln2_g[d] + p.ln2_b[d];
    sm.xs[wid][d] = xv;
    const float* W1T = p.wt + 3 * DD * DD;
    const float* W2T = p.wt + 4 * DD * DD;
    float a = p.b1[d];
#pragma unroll 8
    for (int j = 0; j < DD; ++j) a = fmaf(sm.xs[wid][j], W1T[j * DD + d], a);
    sm.hs[wid][d] = fmaxf(a, 0.0f);
    float o = p.b2[d];
#pragma unroll 8
    for (int j = 0; j < DD; ++j) o = fmaf(sm.hs[wid][j], W2T[j * DD + d], o);
    float res = xv + o;
    if (p.log_ids[row] == 0) res = 0.0f;
    float m2 = waveSum(res) * (1.0f / 64.0f);
    float c2 = res - m2;
    float var2 = waveSum(c2 * c2) * (1.0f / 64.0f);
    float qv = (c2 / sqrtf(var2 + 1e-8f)) * p.ln1_g[DD + d] + p.ln1_b[DD + d];
    sm.qs[wid][d] = qv;
    sm.xs[wid][d] = res;
    p.q[(size_t)row * DD + d] = qv;
    const float* WqT = p.wt + 5 * DD * DD;
    const float* WkT = p.wt + 6 * DD * DD;
    const float* WvT = p.wt + 7 * DD * DD;
    float aq = p.bq[DD + d], ak = p.bk[DD + d], av = p.bv[DD + d];
#pragma unroll 8
    for (int j = 0; j < DD; ++j) {
        aq = fmaf(sm.qs[wid][j], WqT[j * DD + d], aq);
        ak = fmaf(sm.xs[wid][j], WkT[j * DD + d], ak);
        av = fmaf(sm.xs[wid][j], WvT[j * DD + d], av);
    }
    p.Qb[(size_t)row * DD + d] = aq;
    p.Kb[(size_t)row * DD + d] = ak + p.posK[l * DD + d];
    p.Vb[(size_t)row * DD + d] = av + p.posV[l * DD + d];
    sm.Qsh[wid][d] = aq;
    __syncthreads();
    qt_tail(sm.Qsh, p.tKT, p.Qt, u * 4);
    __syncthreads();
}

__device__ void phaseE(RowS& sm, const Params& p, int u) {
    int tid = threadIdx.x, wid = tid >> 6, d = tid & 63;
    int row = u * 4 + wid;
    float v = p.q[(size_t)row * DD + d] + p.att[(size_t)row * DD + d];
    float m = waveSum(v) * (1.0f / 64.0f);
    float c = v - m;
    float var = waveSum(c * c) * (1.0f / 64.0f);
    float xv = (c / sqrtf(var + 1e-8f)) * p.ln2_g[DD + d] + p.ln2_b[DD + d];
    sm.xs[wid][d] = xv;
    const float* W1T = p.wt + 8 * DD * DD;
    const float* W2T = p.wt + 9 * DD * DD;
    float a = p.b1[DD + d];
#pragma unroll 8
    for (int j = 0; j < DD; ++j) a = fmaf(sm.xs[wid][j], W1T[j * DD + d], a);
    sm.hs[wid][d] = fmaxf(a, 0.0f);
    float o = p.b2[DD + d];
#pragma unroll 8
    for (int j = 0; j < DD; ++j) o = fmaf(sm.hs[wid][j], W2T[j * DD + d], o);
    float res = xv + o;
    if (p.log_ids[row] == 0) res = 0.0f;
    float m2 = waveSum(res) * (1.0f / 64.0f);
    float c2 = res - m2;
    float var2 = waveSum(c2 * c2) * (1.0f / 64.0f);
    float f = (c2 / sqrtf(var2 + 1e-8f)) * p.lnf_g[d] + p.lnf_b[d];
    int pid = p.pos_ids[row];
    int nid = p.neg_ids[row];
    float pl = waveSum(f * p.item_emb[(size_t)pid * DD + d]);
    float nl = waveSum(f * p.item_emb[(size_t)nid * DD + d]);
    if (d == 0) {
        p.out[row] = pl;
        p.out[BB * LLEN + row] = nl;
    }
    __syncthreads();
}

// ---- persistent megakernel (regular launch + software grid barrier) ----
__global__ void __launch_bounds__(256, 7) mega_kernel(Params p) {
    __shared__ union { RowS r; AttnS a; } sm;
    for (int m = blockIdx.x; m < 11; m += gridDim.x) phaseT(p, m);
    gridBarrier(p.cnt, p.gen, p.nblk);
    for (int u = blockIdx.x; u < NUNITS; u += gridDim.x) phaseA(sm.r, p, u);
    gridBarrier(p.cnt, p.gen, p.nblk);
    for (int u = blockIdx.x; u < NUNITS; u += gridDim.x) phaseAttn(sm.a, p, u);
    gridBarrier(p.cnt, p.gen, p.nblk);
    for (int u = blockIdx.x; u < NUNITS; u += gridDim.x) phaseC(sm.r, p, u);
    gridBarrier(p.cnt, p.gen, p.nblk);
    for (int u = blockIdx.x; u < NUNITS; u += gridDim.x) phaseAttn(sm.a, p, u);
    gridBarrier(p.cnt, p.gen, p.nblk);
    for (int u = blockIdx.x; u < NUNITS; u += gridDim.x) phaseE(sm.r, p, u);
}

// ---- fallback standalone kernels (R9 6-launch path) ----
__global__ void kT(Params p) { phaseT(p, blockIdx.x); }
__global__ void kA(Params p) { __shared__ RowS s; phaseA(s, p, blockIdx.x); }
__global__ void kAttn(Params p) { __shared__ AttnS s; phaseAttn(s, p, blockIdx.x); }
__global__ void kC(Params p) { __shared__ RowS s; phaseC(s, p, blockIdx.x); }
__global__ void kE(Params p) { __shared__ RowS s; phaseE(s, p, blockIdx.x); }

extern "C" void kernel_launch(void* const* d_in, const int* in_sizes, int n_in,
                              void* d_out, int out_size, void* d_ws, size_t ws_size,
                              hipStream_t stream) {
    Params prm;
    prm.log_ids = (const int*)d_in[0];
    prm.log_times = (const int*)d_in[1];
    prm.pos_ids = (const int*)d_in[2];
    prm.neg_ids = (const int*)d_in[3];
    prm.item_emb = (const float*)d_in[4];
    prm.posK = (const float*)d_in[5];
    prm.posV = (const float*)d_in[6];
    prm.tK_emb = (const float*)d_in[7];
    prm.tV_emb = (const float*)d_in[8];
    prm.ln1_g = (const float*)d_in[9];
    prm.ln1_b = (const float*)d_in[10];
    prm.Wq = (const float*)d_in[11];
    prm.bq = (const float*)d_in[12];
    prm.Wk = (const float*)d_in[13];
    prm.bk = (const float*)d_in[14];
    prm.Wv = (const float*)d_in[15];
    prm.bv = (const float*)d_in[16];
    prm.ln2_g = (const float*)d_in[17];
    prm.ln2_b = (const float*)d_in[18];
    prm.W1 = (const float*)d_in[19];
    prm.b1 = (const float*)d_in[20];
    prm.W2 = (const float*)d_in[21];
    prm.b2 = (const float*)d_in[22];
    prm.lnf_g = (const float*)d_in[23];
    prm.lnf_b = (const float*)d_in[24];

    float* ws = (float*)d_ws;
    prm.q = ws;
    prm.Qb = prm.q + BLD;
    prm.Kb = prm.Qb + BLD;
    prm.Vb = prm.Kb + BLD;
    prm.att = prm.Vb + BLD;
    prm.wt = prm.att + BLD;              // 10 x 64x64 transposed weights
    prm.tKT = prm.wt + 10 * DD * DD;     // [64][366]
    prm.Qt = prm.tKT + DD * TSPAN1;      // [6400][732]
    float* endf = prm.Qt + (size_t)6400 * (2 * TSPAN1);
    prm.cnt = (int*)endf;
    prm.gen = prm.cnt + 1;
    prm.out = (float*)d_out;

    // co-residency capacity from the runtime (host-side queries: capture-safe,
    // deterministic across calls)
    int dev = 0;
    (void)hipGetDevice(&dev);
    int nCU = 0;
    (void)hipDeviceGetAttribute(&nCU, hipDeviceAttributeMultiprocessorCount, dev);
    int maxb = 0;
    hipError_t oe = hipOccupancyMaxActiveBlocksPerMultiprocessor(
        &maxb, (const void*)mega_kernel, 256, 0);

    if (oe == hipSuccess && maxb > 0 && nCU > 0) {
        long cap = (long)maxb * (long)nCU;
        int grid = (int)(cap < NUNITS ? cap : NUNITS);
        prm.nblk = grid;
        (void)hipMemsetAsync(prm.cnt, 0, 2 * sizeof(int), stream);
        mega_kernel<<<grid, 256, 0, stream>>>(prm);
    } else {
        (void)hipGetLastError();  // clear any sticky error
        kT<<<11, 256, 0, stream>>>(prm);
        kA<<<NUNITS, 256, 0, stream>>>(prm);
        kAttn<<<NUNITS, 256, 0, stream>>>(prm);
        kC<<<NUNITS, 256, 0, stream>>>(prm);
        kAttn<<<NUNITS, 256, 0, stream>>>(prm);
        kE<<<NUNITS, 256, 0, stream>>>(prm);
    }
}

// Round 15
// 193.144 us; speedup vs baseline: 4.7930x; 4.7930x over previous
//
#include <hip/hip_runtime.h>
#include <math.h>

// TiSASRec forward on MI355X — round 14:
//  - R13 post-mortem: persistent megakernel = 1123us (sw grid-barrier across
//    8 XCDs costs ~150us each). Megakernel abandoned; back to R9 6-launch.
//  - Surgical change vs R9 (183us): attn phase-3 vectorized with BROADCAST
//    float4 sc + ushort4 tm reads (conflict-free, unlike R10's phase-2
//    stride-16B pattern that caused 674K conflicts) + float2 V/tV loads +
//    float4 qt_s staging. Phase 1 & 2 byte-identical to R9.
// B=32, L=200, D=64, H=2, dh=32, NL=2.
#define BB 32
#define LLEN 200
#define DD 64
#define HH 2
#define NLAYER 2
#define BLD (BB * LLEN * DD)
#define TSPAN1 366   // TIME_SPAN+1

__device__ inline float waveSum(float v) {
#pragma unroll
    for (int off = 32; off > 0; off >>= 1) v += __shfl_xor(v, off);
    return v;
}
__device__ inline float halfSum(float v) {
    v += __shfl_xor(v, 1);
    v += __shfl_xor(v, 2);
    v += __shfl_xor(v, 4);
    v += __shfl_xor(v, 8);
    v += __shfl_xor(v, 16);
    return v;
}
__device__ inline float halfMax(float v) {
    v = fmaxf(v, __shfl_xor(v, 1));
    v = fmaxf(v, __shfl_xor(v, 2));
    v = fmaxf(v, __shfl_xor(v, 4));
    v = fmaxf(v, __shfl_xor(v, 8));
    v = fmaxf(v, __shfl_xor(v, 16));
    return v;
}

// qt tail: block computed Qsh[4][64] for rows base..base+3; thread t owns
// bucket t (coalesced tKT column reads); Qt[row][h*366+t] = Qsh[r].tK[t] (head h)
__device__ inline void qt_tail(const float (*Qsh)[DD], const float* __restrict__ tKT,
                               float* __restrict__ Qt_g, int base) {
    int tid = threadIdx.x;
    for (int t = tid; t < TSPAN1; t += 256) {
        const float* tk = tKT + t;
        float a0 = 0, a1 = 0, a2 = 0, a3 = 0;
#pragma unroll 8
        for (int d = 0; d < 32; ++d) {
            float v = tk[d * TSPAN1];
            a0 = fmaf(v, Qsh[0][d], a0);
            a1 = fmaf(v, Qsh[1][d], a1);
            a2 = fmaf(v, Qsh[2][d], a2);
            a3 = fmaf(v, Qsh[3][d], a3);
        }
        Qt_g[(size_t)(base + 0) * (2 * TSPAN1) + t] = a0;
        Qt_g[(size_t)(base + 1) * (2 * TSPAN1) + t] = a1;
        Qt_g[(size_t)(base + 2) * (2 * TSPAN1) + t] = a2;
        Qt_g[(size_t)(base + 3) * (2 * TSPAN1) + t] = a3;
        float b0 = 0, b1 = 0, b2 = 0, b3 = 0;
#pragma unroll 8
        for (int d = 32; d < 64; ++d) {
            float v = tk[d * TSPAN1];
            b0 = fmaf(v, Qsh[0][d], b0);
            b1 = fmaf(v, Qsh[1][d], b1);
            b2 = fmaf(v, Qsh[2][d], b2);
            b3 = fmaf(v, Qsh[3][d], b3);
        }
        Qt_g[(size_t)(base + 0) * (2 * TSPAN1) + TSPAN1 + t] = b0;
        Qt_g[(size_t)(base + 1) * (2 * TSPAN1) + TSPAN1 + t] = b1;
        Qt_g[(size_t)(base + 2) * (2 * TSPAN1) + TSPAN1 + t] = b2;
        Qt_g[(size_t)(base + 3) * (2 * TSPAN1) + TSPAN1 + t] = b3;
    }
}

// grid=11: m<10 -> transpose 64x64 weights; m==10 -> tK_emb^T [64][366]
__global__ void transpose_kernel(const float* __restrict__ Wq,
                                 const float* __restrict__ Wk,
                                 const float* __restrict__ Wv,
                                 const float* __restrict__ W1,
                                 const float* __restrict__ W2,
                                 const float* __restrict__ tK_emb,
                                 float* __restrict__ wt,
                                 float* __restrict__ tKT) {
    int m = blockIdx.x;
    if (m < 10) {
        const float* src;
        switch (m % 5) {
            case 0: src = Wq; break;
            case 1: src = Wk; break;
            case 2: src = Wv; break;
            case 3: src = W1; break;
            default: src = W2; break;
        }
        src += (m / 5) * DD * DD;
        float* dst = wt + m * DD * DD;
        for (int e = threadIdx.x; e < DD * DD; e += 256) {
            int d = e >> 6, j = e & 63;
            dst[j * DD + d] = src[e];
        }
    } else {
        for (int e = threadIdx.x; e < TSPAN1 * DD; e += 256) {
            int t = e >> 6, d = e & 63;
            tKT[d * TSPAN1 + t] = tK_emb[e];
        }
    }
}

// Layer-0 entry + fused qt: 4 rows/block, wave per row. Embedding fused.
__global__ void ln_qkv_kernel(const int* __restrict__ log_ids,
                              const float* __restrict__ item_emb,
                              const float* __restrict__ g,
                              const float* __restrict__ bln,
                              const float* __restrict__ WqT, const float* __restrict__ bq,
                              const float* __restrict__ WkT, const float* __restrict__ bk,
                              const float* __restrict__ WvT, const float* __restrict__ bv,
                              const float* __restrict__ posK,
                              const float* __restrict__ posV,
                              const float* __restrict__ tKT,
                              float* __restrict__ q,
                              float* __restrict__ Q, float* __restrict__ K,
                              float* __restrict__ V,
                              float* __restrict__ Qt_g) {
    __shared__ float qs[4][DD], xs[4][DD], Qsh[4][DD];
    int tid = threadIdx.x;
    int wid = tid >> 6, d = tid & 63;
    int row = blockIdx.x * 4 + wid;
    int l = row % LLEN;
    int id = log_ids[row];
    float xv = (id == 0) ? 0.0f : item_emb[(size_t)id * DD + d] * 8.0f;  // sqrt(64)*keep
    xs[wid][d] = xv;
    float m = waveSum(xv) * (1.0f / 64.0f);
    float c = xv - m;
    float var = waveSum(c * c) * (1.0f / 64.0f);
    float qv = (c / sqrtf(var + 1e-8f)) * g[d] + bln[d];
    qs[wid][d] = qv;
    q[(size_t)row * DD + d] = qv;
    float aq = bq[d], ak = bk[d], av = bv[d];
#pragma unroll 8
    for (int j = 0; j < DD; ++j) {
        aq = fmaf(qs[wid][j], WqT[j * DD + d], aq);
        ak = fmaf(xs[wid][j], WkT[j * DD + d], ak);
        av = fmaf(xs[wid][j], WvT[j * DD + d], av);
    }
    Q[(size_t)row * DD + d] = aq;
    K[(size_t)row * DD + d] = ak + posK[l * DD + d];
    V[(size_t)row * DD + d] = av + posV[l * DD + d];
    Qsh[wid][d] = aq;
    __syncthreads();
    qt_tail(Qsh, tKT, Qt_g, blockIdx.x * 4);
}

// Attention: wave-per-query {i,99-i,100+i,199-i}; per-wave phases.
// Phase 1/2: R9-exact. Phase 3: broadcast float4/ushort4 + float2 V loads.
__global__ void attn_kernel(const float* __restrict__ Q,
                            const float* __restrict__ Keff,
                            const float* __restrict__ Veff,
                            const int* __restrict__ log_times,
                            const float* __restrict__ Qt_g,
                            const float* __restrict__ tV_emb,
                            float* __restrict__ out) {
    __shared__ int t_s[LLEN];
    __shared__ __align__(16) float sc[4][HH][LLEN];
    __shared__ __align__(16) unsigned short tm_s[4][LLEN];
    __shared__ __align__(16) float qt_s[4][2 * TSPAN1];

    int tid = threadIdx.x;
    int wid = tid >> 6;
    int lane = tid & 63;
    int bi = blockIdx.x / 50;
    int i = blockIdx.x % 50;
    int qi = (wid == 0) ? i : (wid == 1) ? (99 - i) : (wid == 2) ? (100 + i) : (199 - i);
    int row = bi * LLEN + qi;
    int len = qi + 1;

    if (tid < LLEN) t_s[tid] = log_times[bi * LLEN + tid];
    __syncthreads();

    // stage this query's Qt row (732 floats = 183 float4) into LDS
    {
        const float4* qtrow4 = (const float4*)(Qt_g + (size_t)row * (2 * TSPAN1));
        float4* qts4 = (float4*)&qt_s[wid][0];
        for (int e = lane; e < 183; e += 64) qts4[e] = qtrow4[e];
    }

    // bucket table for this query
    int tq = t_s[qi];
    for (int k = lane; k < len; k += 64) {
        int dt = tq - t_s[k];
        if (dt < 0) dt = -dt;
        float dtf = fminf((float)dt * (1.0f / 86400.0f), 365.0f);
        tm_s[wid][k] = (unsigned short)(int)dtf;
    }

    int h = lane >> 5;       // head
    int l5 = lane & 31;
    int cch = l5 >> 2;       // channel chunk 0..7
    int jo = l5 & 3;         // key offset in group
    float4 qv = ((const float4*)(Q + (size_t)row * DD))[h * 8 + cch];
    const float4* K4 = (const float4*)(Keff + (size_t)bi * LLEN * DD);
    const float scale = 0.17677669529663687f;  // 1/sqrt(32)

    // phase 1 (R9-exact): scores, 4 keys per iteration
    for (int k0 = 0; k0 < len; k0 += 4) {
        int k = k0 + jo;
        int kc = (k < len) ? k : (len - 1);
        int bucket = tm_s[wid][kc];
        float4 kv = K4[kc * 16 + h * 8 + cch];
        float p = qv.x * kv.x + qv.y * kv.y + qv.z * kv.z + qv.w * kv.w;
        p += __shfl_xor(p, 4);
        p += __shfl_xor(p, 8);
        p += __shfl_xor(p, 16);   // full 32-dot for (h, key k)
        float s = (p + qt_s[wid][h * TSPAN1 + bucket]) * scale;
        if (cch == 0 && k < len) sc[wid][h][k] = s;
    }

    // phase 2 (R9-exact): softmax (lanes 0..31 head 0, 32..63 head 1)
    {
        float m = -INFINITY;
        for (int k = l5; k < len; k += 32) m = fmaxf(m, sc[wid][h][k]);
        m = halfMax(m);
        float s = 0.0f;
        for (int k = l5; k < len; k += 32) {
            float e = expf(sc[wid][h][k] - m);
            sc[wid][h][k] = e;
            s += e;
        }
        s = halfSum(s);
        float inv = 1.0f / s;
        for (int k = l5; k < len; k += 32) sc[wid][h][k] *= inv;
    }

    // phase 3 (vectorized): lane = channel pair (float2), half-wave = key
    // parity. Per 4 keys: 1 broadcast float4 sc + 1 broadcast ushort4 tm +
    // 4 float2 VMEM per lane. Broadcast LDS reads are conflict-free.
    const float2* V2 = (const float2*)(Veff + (size_t)bi * LLEN * DD);
    const float2* tV2 = (const float2*)tV_emb;
    int l5x = lane & 31;          // channel-pair index (channels 2*l5x, 2*l5x+1)
    int kh = lane >> 5;           // which key of the pair
    int h2 = l5x >> 4;            // head of these channels
    float acc0x = 0, acc0y = 0, acc1x = 0, acc1y = 0;
    int k = 0;
    for (; k + 4 <= len; k += 4) {
        float4 a4 = *(const float4*)&sc[wid][h2][k];
        ushort4 t4 = *(const ushort4*)&tm_s[wid][k];
        float aA = kh ? a4.y : a4.x;
        float aB = kh ? a4.w : a4.z;
        int bA = kh ? (int)t4.y : (int)t4.x;
        int bB = kh ? (int)t4.w : (int)t4.z;
        float2 v0 = V2[(k + kh) * 32 + l5x];
        float2 tv0 = tV2[bA * 32 + l5x];
        float2 v1 = V2[(k + 2 + kh) * 32 + l5x];
        float2 tv1 = tV2[bB * 32 + l5x];
        acc0x = fmaf(aA, v0.x + tv0.x, acc0x);
        acc0y = fmaf(aA, v0.y + tv0.y, acc0y);
        acc1x = fmaf(aB, v1.x + tv1.x, acc1x);
        acc1y = fmaf(aB, v1.y + tv1.y, acc1y);
    }
    if (kh == 0) {  // tail: lanes 0..31 handle remaining <4 keys
        for (; k < len; ++k) {
            float a = sc[wid][h2][k];
            int b = tm_s[wid][k];
            float2 vv = V2[k * 32 + l5x];
            float2 tv = tV2[b * 32 + l5x];
            acc0x = fmaf(a, vv.x + tv.x, acc0x);
            acc0y = fmaf(a, vv.y + tv.y, acc0y);
        }
    }
    float ox = acc0x + acc1x;
    float oy = acc0y + acc1y;
    ox += __shfl_xor(ox, 32);
    oy += __shfl_xor(oy, 32);
    if (kh == 0) {
        float2 o2; o2.x = ox; o2.y = oy;
        *(float2*)&out[(size_t)row * DD + 2 * l5x] = o2;
    }
}

// MID + fused qt: addln_ffn(layer i) + ln_qkv(layer i+1) + qt tail.
__global__ void mid_kernel(const float* __restrict__ qin,
                           const float* __restrict__ att,
                           const float* __restrict__ g2, const float* __restrict__ b2ln,
                           const float* __restrict__ W1T, const float* __restrict__ b1v,
                           const float* __restrict__ W2T, const float* __restrict__ b2v,
                           const int* __restrict__ log_ids,
                           const float* __restrict__ g1n, const float* __restrict__ b1n,
                           const float* __restrict__ WqT, const float* __restrict__ bq,
                           const float* __restrict__ WkT, const float* __restrict__ bk,
                           const float* __restrict__ WvT, const float* __restrict__ bv,
                           const float* __restrict__ posK,
                           const float* __restrict__ posV,
                           const float* __restrict__ tKT,
                           float* __restrict__ q,
                           float* __restrict__ Q, float* __restrict__ K,
                           float* __restrict__ V,
                           float* __restrict__ Qt_g) {
    __shared__ float xs[4][DD], hs[4][DD], qs[4][DD], Qsh[4][DD];
    int tid = threadIdx.x;
    int wid = tid >> 6, d = tid & 63;
    int row = blockIdx.x * 4 + wid;
    int l = row % LLEN;
    // --- addln + FFN ---
    float v = qin[(size_t)row * DD + d] + att[(size_t)row * DD + d];
    float m = waveSum(v) * (1.0f / 64.0f);
    float c = v - m;
    float var = waveSum(c * c) * (1.0f / 64.0f);
    float xv = (c / sqrtf(var + 1e-8f)) * g2[d] + b2ln[d];
    xs[wid][d] = xv;
    float a = b1v[d];
#pragma unroll 8
    for (int j = 0; j < DD; ++j) a = fmaf(xs[wid][j], W1T[j * DD + d], a);
    hs[wid][d] = fmaxf(a, 0.0f);
    float o = b2v[d];
#pragma unroll 8
    for (int j = 0; j < DD; ++j) o = fmaf(hs[wid][j], W2T[j * DD + d], o);
    float res = xv + o;
    if (log_ids[row] == 0) res = 0.0f;
    // --- next layer: LN1 + QKV projection ---
    float m2 = waveSum(res) * (1.0f / 64.0f);
    float c2 = res - m2;
    float var2 = waveSum(c2 * c2) * (1.0f / 64.0f);
    float qv = (c2 / sqrtf(var2 + 1e-8f)) * g1n[d] + b1n[d];
    qs[wid][d] = qv;
    xs[wid][d] = res;
    q[(size_t)row * DD + d] = qv;
    float aq = bq[d], ak = bk[d], av = bv[d];
#pragma unroll 8
    for (int j = 0; j < DD; ++j) {
        aq = fmaf(qs[wid][j], WqT[j * DD + d], aq);
        ak = fmaf(xs[wid][j], WkT[j * DD + d], ak);
        av = fmaf(xs[wid][j], WvT[j * DD + d], av);
    }
    Q[(size_t)row * DD + d] = aq;
    K[(size_t)row * DD + d] = ak + posK[l * DD + d];
    V[(size_t)row * DD + d] = av + posV[l * DD + d];
    Qsh[wid][d] = aq;
    __syncthreads();
    qt_tail(Qsh, tKT, Qt_g, blockIdx.x * 4);
}

// END: addln_ffn(last layer) fused with final LN + logits. 4 rows/block.
__global__ void end_kernel(const float* __restrict__ qin,
                           const float* __restrict__ att,
                           const float* __restrict__ g2, const float* __restrict__ b2ln,
                           const float* __restrict__ W1T, const float* __restrict__ b1v,
                           const float* __restrict__ W2T, const float* __restrict__ b2v,
                           const int* __restrict__ log_ids,
                           const float* __restrict__ lnf_g, const float* __restrict__ lnf_b,
                           const float* __restrict__ item_emb,
                           const int* __restrict__ pos_ids,
                           const int* __restrict__ neg_ids,
                           float* __restrict__ out) {
    __shared__ float xs[4][DD], hs[4][DD];
    int tid = threadIdx.x;
    int wid = tid >> 6, d = tid & 63;
    int row = blockIdx.x * 4 + wid;
    float v = qin[(size_t)row * DD + d] + att[(size_t)row * DD + d];
    float m = waveSum(v) * (1.0f / 64.0f);
    float c = v - m;
    float var = waveSum(c * c) * (1.0f / 64.0f);
    float xv = (c / sqrtf(var + 1e-8f)) * g2[d] + b2ln[d];
    xs[wid][d] = xv;
    float a = b1v[d];
#pragma unroll 8
    for (int j = 0; j < DD; ++j) a = fmaf(xs[wid][j], W1T[j * DD + d], a);
    hs[wid][d] = fmaxf(a, 0.0f);
    float o = b2v[d];
#pragma unroll 8
    for (int j = 0; j < DD; ++j) o = fmaf(hs[wid][j], W2T[j * DD + d], o);
    float res = xv + o;
    if (log_ids[row] == 0) res = 0.0f;
    // --- final LN + logits ---
    float m2 = waveSum(res) * (1.0f / 64.0f);
    float c2 = res - m2;
    float var2 = waveSum(c2 * c2) * (1.0f / 64.0f);
    float f = (c2 / sqrtf(var2 + 1e-8f)) * lnf_g[d] + lnf_b[d];
    int pid = pos_ids[row];
    int nid = neg_ids[row];
    float p = waveSum(f * item_emb[(size_t)pid * DD + d]);
    float n = waveSum(f * item_emb[(size_t)nid * DD + d]);
    if (d == 0) {
        out[row] = p;
        out[BB * LLEN + row] = n;
    }
}

extern "C" void kernel_launch(void* const* d_in, const int* in_sizes, int n_in,
                              void* d_out, int out_size, void* d_ws, size_t ws_size,
                              hipStream_t stream) {
    const int* log_ids = (const int*)d_in[0];
    const int* log_times = (const int*)d_in[1];
    const int* pos_ids = (const int*)d_in[2];
    const int* neg_ids = (const int*)d_in[3];
    const float* item_emb = (const float*)d_in[4];
    const float* posK = (const float*)d_in[5];
    const float* posV = (const float*)d_in[6];
    const float* tK_emb = (const float*)d_in[7];
    const float* tV_emb = (const float*)d_in[8];
    const float* ln1_g = (const float*)d_in[9];
    const float* ln1_b = (const float*)d_in[10];
    const float* Wq = (const float*)d_in[11];
    const float* bq = (const float*)d_in[12];
    const float* Wk = (const float*)d_in[13];
    const float* bk = (const float*)d_in[14];
    const float* Wv = (const float*)d_in[15];
    const float* bv = (const float*)d_in[16];
    const float* ln2_g = (const float*)d_in[17];
    const float* ln2_b = (const float*)d_in[18];
    const float* W1 = (const float*)d_in[19];
    const float* b1 = (const float*)d_in[20];
    const float* W2 = (const float*)d_in[21];
    const float* b2 = (const float*)d_in[22];
    const float* lnf_g = (const float*)d_in[23];
    const float* lnf_b = (const float*)d_in[24];

    float* ws = (float*)d_ws;
    float* q = ws;                        // ln1 output (residual)
    float* Qb = q + BLD;
    float* Kb = Qb + BLD;
    float* Vb = Kb + BLD;
    float* att = Vb + BLD;
    float* wt = att + BLD;                // 10 x 64x64 transposed weights
    float* tKT = wt + 10 * DD * DD;       // [64][366]
    float* Qt = tKT + DD * TSPAN1;        // [6400][732]

    const int nrow = BB * LLEN;           // 6400

    const float* W1T0 = wt + 3 * DD * DD;
    const float* W2T0 = wt + 4 * DD * DD;
    const float* W1T1 = wt + 8 * DD * DD;
    const float* W2T1 = wt + 9 * DD * DD;

    transpose_kernel<<<11, 256, 0, stream>>>(Wq, Wk, Wv, W1, W2, tK_emb, wt, tKT);

    // layer 0 entry (embed + qt fused)
    ln_qkv_kernel<<<nrow / 4, 256, 0, stream>>>(log_ids, item_emb,
                                                ln1_g, ln1_b,
                                                wt + 0 * DD * DD, bq,
                                                wt + 1 * DD * DD, bk,
                                                wt + 2 * DD * DD, bv,
                                                posK, posV, tKT,
                                                q, Qb, Kb, Vb, Qt);
    attn_kernel<<<BB * 50, 256, 0, stream>>>(Qb, Kb, Vb, log_times, Qt, tV_emb, att);

    // layer 0 tail + layer 1 entry (+ qt fused)
    mid_kernel<<<nrow / 4, 256, 0, stream>>>(q, att,
                                             ln2_g, ln2_b,
                                             W1T0, b1, W2T0, b2,
                                             log_ids,
                                             ln1_g + DD, ln1_b + DD,
                                             wt + 5 * DD * DD, bq + DD,
                                             wt + 6 * DD * DD, bk + DD,
                                             wt + 7 * DD * DD, bv + DD,
                                             posK, posV, tKT,
                                             q, Qb, Kb, Vb, Qt);
    attn_kernel<<<BB * 50, 256, 0, stream>>>(Qb, Kb, Vb, log_times, Qt, tV_emb, att);

    // layer 1 tail + final logits
    end_kernel<<<nrow / 4, 256, 0, stream>>>(q, att,
                                             ln2_g + DD, ln2_b + DD,
                                             W1T1, b1 + DD, W2T1, b2 + DD,
                                             log_ids,
                                             lnf_g, lnf_b, item_emb,
                                             pos_ids, neg_ids, (float*)d_out);
}

// Round 16
// 179.374 us; speedup vs baseline: 5.1610x; 1.0768x over previous
//
#include <hip/hip_runtime.h>
#include <math.h>

// TiSASRec forward on MI355X — round 15:
//  - Base: R9-exact (best measured: 183.3us; attn 47.6us). Five attn
//    restructures (R5/R8/R10/R13/R14) all regressed — loop bodies frozen.
//  - Single change: Qt table stored in BF16 (RNE). Halves the 18.7MB Qt
//    HBM stream (attn's dominant FETCH), producer writes, staging DS ops
//    (732 scalar -> 183x8B), and qt_s LDS (11.7->5.9KB). Lookup adds
//    shift+cast (~100 VALU/wave). Score perturbation ~1e-3 << 2.67e-2 tol.
// B=32, L=200, D=64, H=2, dh=32, NL=2.
#define BB 32
#define LLEN 200
#define DD 64
#define HH 2
#define NLAYER 2
#define BLD (BB * LLEN * DD)
#define TSPAN1 366   // TIME_SPAN+1
#define QTROW (2 * TSPAN1)   // 732 bf16 per row

__device__ inline float waveSum(float v) {
#pragma unroll
    for (int off = 32; off > 0; off >>= 1) v += __shfl_xor(v, off);
    return v;
}
__device__ inline float halfSum(float v) {
    v += __shfl_xor(v, 1);
    v += __shfl_xor(v, 2);
    v += __shfl_xor(v, 4);
    v += __shfl_xor(v, 8);
    v += __shfl_xor(v, 16);
    return v;
}
__device__ inline float halfMax(float v) {
    v = fmaxf(v, __shfl_xor(v, 1));
    v = fmaxf(v, __shfl_xor(v, 2));
    v = fmaxf(v, __shfl_xor(v, 4));
    v = fmaxf(v, __shfl_xor(v, 8));
    v = fmaxf(v, __shfl_xor(v, 16));
    return v;
}

// f32 -> bf16 with round-to-nearest-even
__device__ inline unsigned short f2bf(float f) {
    unsigned u = __float_as_uint(f);
    u = (u + 0x7FFFu + ((u >> 16) & 1u)) >> 16;
    return (unsigned short)u;
}
__device__ inline float bf2f(unsigned short b) {
    return __uint_as_float(((unsigned)b) << 16);
}

// qt tail (R9 structure): thread t owns bucket t (coalesced tKT column
// reads); Qt[row][h*366+t] = Qsh[r] . tK[t] (head h), stored bf16.
__device__ inline void qt_tail(const float (*Qsh)[DD], const float* __restrict__ tKT,
                               unsigned short* __restrict__ Qt_g, int base) {
    int tid = threadIdx.x;
    for (int t = tid; t < TSPAN1; t += 256) {
        const float* tk = tKT + t;
        float a0 = 0, a1 = 0, a2 = 0, a3 = 0;
#pragma unroll 8
        for (int d = 0; d < 32; ++d) {
            float v = tk[d * TSPAN1];
            a0 = fmaf(v, Qsh[0][d], a0);
            a1 = fmaf(v, Qsh[1][d], a1);
            a2 = fmaf(v, Qsh[2][d], a2);
            a3 = fmaf(v, Qsh[3][d], a3);
        }
        Qt_g[(size_t)(base + 0) * QTROW + t] = f2bf(a0);
        Qt_g[(size_t)(base + 1) * QTROW + t] = f2bf(a1);
        Qt_g[(size_t)(base + 2) * QTROW + t] = f2bf(a2);
        Qt_g[(size_t)(base + 3) * QTROW + t] = f2bf(a3);
        float b0 = 0, b1 = 0, b2 = 0, b3 = 0;
#pragma unroll 8
        for (int d = 32; d < 64; ++d) {
            float v = tk[d * TSPAN1];
            b0 = fmaf(v, Qsh[0][d], b0);
            b1 = fmaf(v, Qsh[1][d], b1);
            b2 = fmaf(v, Qsh[2][d], b2);
            b3 = fmaf(v, Qsh[3][d], b3);
        }
        Qt_g[(size_t)(base + 0) * QTROW + TSPAN1 + t] = f2bf(b0);
        Qt_g[(size_t)(base + 1) * QTROW + TSPAN1 + t] = f2bf(b1);
        Qt_g[(size_t)(base + 2) * QTROW + TSPAN1 + t] = f2bf(b2);
        Qt_g[(size_t)(base + 3) * QTROW + TSPAN1 + t] = f2bf(b3);
    }
}

// grid=11: m<10 -> transpose 64x64 weights; m==10 -> tK_emb^T [64][366]
__global__ void transpose_kernel(const float* __restrict__ Wq,
                                 const float* __restrict__ Wk,
                                 const float* __restrict__ Wv,
                                 const float* __restrict__ W1,
                                 const float* __restrict__ W2,
                                 const float* __restrict__ tK_emb,
                                 float* __restrict__ wt,
                                 float* __restrict__ tKT) {
    int m = blockIdx.x;
    if (m < 10) {
        const float* src;
        switch (m % 5) {
            case 0: src = Wq; break;
            case 1: src = Wk; break;
            case 2: src = Wv; break;
            case 3: src = W1; break;
            default: src = W2; break;
        }
        src += (m / 5) * DD * DD;
        float* dst = wt + m * DD * DD;
        for (int e = threadIdx.x; e < DD * DD; e += 256) {
            int d = e >> 6, j = e & 63;
            dst[j * DD + d] = src[e];
        }
    } else {
        for (int e = threadIdx.x; e < TSPAN1 * DD; e += 256) {
            int t = e >> 6, d = e & 63;
            tKT[d * TSPAN1 + t] = tK_emb[e];
        }
    }
}

// Layer-0 entry + fused qt: 4 rows/block, wave per row. Embedding fused.
__global__ void ln_qkv_kernel(const int* __restrict__ log_ids,
                              const float* __restrict__ item_emb,
                              const float* __restrict__ g,
                              const float* __restrict__ bln,
                              const float* __restrict__ WqT, const float* __restrict__ bq,
                              const float* __restrict__ WkT, const float* __restrict__ bk,
                              const float* __restrict__ WvT, const float* __restrict__ bv,
                              const float* __restrict__ posK,
                              const float* __restrict__ posV,
                              const float* __restrict__ tKT,
                              float* __restrict__ q,
                              float* __restrict__ Q, float* __restrict__ K,
                              float* __restrict__ V,
                              unsigned short* __restrict__ Qt_g) {
    __shared__ float qs[4][DD], xs[4][DD], Qsh[4][DD];
    int tid = threadIdx.x;
    int wid = tid >> 6, d = tid & 63;
    int row = blockIdx.x * 4 + wid;
    int l = row % LLEN;
    int id = log_ids[row];
    float xv = (id == 0) ? 0.0f : item_emb[(size_t)id * DD + d] * 8.0f;  // sqrt(64)*keep
    xs[wid][d] = xv;
    float m = waveSum(xv) * (1.0f / 64.0f);
    float c = xv - m;
    float var = waveSum(c * c) * (1.0f / 64.0f);
    float qv = (c / sqrtf(var + 1e-8f)) * g[d] + bln[d];
    qs[wid][d] = qv;
    q[(size_t)row * DD + d] = qv;
    float aq = bq[d], ak = bk[d], av = bv[d];
#pragma unroll 8
    for (int j = 0; j < DD; ++j) {
        aq = fmaf(qs[wid][j], WqT[j * DD + d], aq);
        ak = fmaf(xs[wid][j], WkT[j * DD + d], ak);
        av = fmaf(xs[wid][j], WvT[j * DD + d], av);
    }
    Q[(size_t)row * DD + d] = aq;
    K[(size_t)row * DD + d] = ak + posK[l * DD + d];
    V[(size_t)row * DD + d] = av + posV[l * DD + d];
    Qsh[wid][d] = aq;
    __syncthreads();
    qt_tail(Qsh, tKT, Qt_g, blockIdx.x * 4);
}

// Attention (R9 structure; qt in bf16). wave-per-query {i,99-i,100+i,199-i};
// per-wave phases; qt_s staged (bf16, uint2 loads); 4-key score groups.
__global__ void attn_kernel(const float* __restrict__ Q,
                            const float* __restrict__ Keff,
                            const float* __restrict__ Veff,
                            const int* __restrict__ log_times,
                            const unsigned short* __restrict__ Qt_g,
                            const float* __restrict__ tV_emb,
                            float* __restrict__ out) {
    __shared__ int t_s[LLEN];
    __shared__ float sc[4][HH][LLEN];
    __shared__ unsigned short tm_s[4][LLEN];
    __shared__ __align__(8) unsigned short qt_s[4][QTROW];

    int tid = threadIdx.x;
    int wid = tid >> 6;
    int lane = tid & 63;
    int bi = blockIdx.x / 50;
    int i = blockIdx.x % 50;
    int qi = (wid == 0) ? i : (wid == 1) ? (99 - i) : (wid == 2) ? (100 + i) : (199 - i);
    int row = bi * LLEN + qi;
    int len = qi + 1;

    if (tid < LLEN) t_s[tid] = log_times[bi * LLEN + tid];
    __syncthreads();

    // stage this query's Qt row (732 bf16 = 183 uint2) into LDS
    {
        const uint2* qtrow2 = (const uint2*)(Qt_g + (size_t)row * QTROW);
        uint2* qts2 = (uint2*)&qt_s[wid][0];
        for (int e = lane; e < 183; e += 64) qts2[e] = qtrow2[e];
    }

    // bucket table for this query
    int tq = t_s[qi];
    for (int k = lane; k < len; k += 64) {
        int dt = tq - t_s[k];
        if (dt < 0) dt = -dt;
        float dtf = fminf((float)dt * (1.0f / 86400.0f), 365.0f);
        tm_s[wid][k] = (unsigned short)(int)dtf;
    }

    int h = lane >> 5;       // head
    int l5 = lane & 31;
    int cch = l5 >> 2;       // channel chunk 0..7
    int jo = l5 & 3;         // key offset in group
    float4 qv = ((const float4*)(Q + (size_t)row * DD))[h * 8 + cch];
    const float4* K4 = (const float4*)(Keff + (size_t)bi * LLEN * DD);
    const float scale = 0.17677669529663687f;  // 1/sqrt(32)

    // phase 1: scores, 4 keys per iteration
    for (int k0 = 0; k0 < len; k0 += 4) {
        int k = k0 + jo;
        int kc = (k < len) ? k : (len - 1);
        int bucket = tm_s[wid][kc];
        float4 kv = K4[kc * 16 + h * 8 + cch];
        float p = qv.x * kv.x + qv.y * kv.y + qv.z * kv.z + qv.w * kv.w;
        p += __shfl_xor(p, 4);
        p += __shfl_xor(p, 8);
        p += __shfl_xor(p, 16);   // full 32-dot for (h, key k)
        float s = (p + bf2f(qt_s[wid][h * TSPAN1 + bucket])) * scale;
        if (cch == 0 && k < len) sc[wid][h][k] = s;
    }

    // phase 2: softmax (lanes 0..31 head 0, 32..63 head 1; same wave)
    {
        float m = -INFINITY;
        for (int k = l5; k < len; k += 32) m = fmaxf(m, sc[wid][h][k]);
        m = halfMax(m);
        float s = 0.0f;
        for (int k = l5; k < len; k += 32) {
            float e = expf(sc[wid][h][k] - m);
            sc[wid][h][k] = e;
            s += e;
        }
        s = halfSum(s);
        float inv = 1.0f / s;
        for (int k = l5; k < len; k += 32) sc[wid][h][k] *= inv;
    }

    // phase 3: out[d] = sum_k A[h][k] * (V_eff[k][d] + tV[bucket[k]][d])
    const float* Vb = Veff + (size_t)bi * LLEN * DD + lane;
    const float* tVl = tV_emb + lane;
    float acc0 = 0.0f, acc1 = 0.0f, acc2 = 0.0f, acc3 = 0.0f;
    int k = 0;
    for (; k + 4 <= len; k += 4) {
        int b0 = tm_s[wid][k + 0];
        int b1 = tm_s[wid][k + 1];
        int b2 = tm_s[wid][k + 2];
        int b3 = tm_s[wid][k + 3];
        float a0 = sc[wid][h][k + 0];
        float a1 = sc[wid][h][k + 1];
        float a2 = sc[wid][h][k + 2];
        float a3 = sc[wid][h][k + 3];
        acc0 = fmaf(a0, Vb[(k + 0) * DD] + tVl[b0 * DD], acc0);
        acc1 = fmaf(a1, Vb[(k + 1) * DD] + tVl[b1 * DD], acc1);
        acc2 = fmaf(a2, Vb[(k + 2) * DD] + tVl[b2 * DD], acc2);
        acc3 = fmaf(a3, Vb[(k + 3) * DD] + tVl[b3 * DD], acc3);
    }
    for (; k < len; ++k) {
        int b0 = tm_s[wid][k];
        acc0 = fmaf(sc[wid][h][k], Vb[k * DD] + tVl[b0 * DD], acc0);
    }
    out[(size_t)row * DD + lane] = (acc0 + acc1) + (acc2 + acc3);
}

// MID + fused qt: addln_ffn(layer i) + ln_qkv(layer i+1) + qt tail.
__global__ void mid_kernel(const float* __restrict__ qin,
                           const float* __restrict__ att,
                           const float* __restrict__ g2, const float* __restrict__ b2ln,
                           const float* __restrict__ W1T, const float* __restrict__ b1v,
                           const float* __restrict__ W2T, const float* __restrict__ b2v,
                           const int* __restrict__ log_ids,
                           const float* __restrict__ g1n, const float* __restrict__ b1n,
                           const float* __restrict__ WqT, const float* __restrict__ bq,
                           const float* __restrict__ WkT, const float* __restrict__ bk,
                           const float* __restrict__ WvT, const float* __restrict__ bv,
                           const float* __restrict__ posK,
                           const float* __restrict__ posV,
                           const float* __restrict__ tKT,
                           float* __restrict__ q,
                           float* __restrict__ Q, float* __restrict__ K,
                           float* __restrict__ V,
                           unsigned short* __restrict__ Qt_g) {
    __shared__ float xs[4][DD], hs[4][DD], qs[4][DD], Qsh[4][DD];
    int tid = threadIdx.x;
    int wid = tid >> 6, d = tid & 63;
    int row = blockIdx.x * 4 + wid;
    int l = row % LLEN;
    // --- addln + FFN ---
    float v = qin[(size_t)row * DD + d] + att[(size_t)row * DD + d];
    float m = waveSum(v) * (1.0f / 64.0f);
    float c = v - m;
    float var = waveSum(c * c) * (1.0f / 64.0f);
    float xv = (c / sqrtf(var + 1e-8f)) * g2[d] + b2ln[d];
    xs[wid][d] = xv;
    float a = b1v[d];
#pragma unroll 8
    for (int j = 0; j < DD; ++j) a = fmaf(xs[wid][j], W1T[j * DD + d], a);
    hs[wid][d] = fmaxf(a, 0.0f);
    float o = b2v[d];
#pragma unroll 8
    for (int j = 0; j < DD; ++j) o = fmaf(hs[wid][j], W2T[j * DD + d], o);
    float res = xv + o;
    if (log_ids[row] == 0) res = 0.0f;
    // --- next layer: LN1 + QKV projection ---
    float m2 = waveSum(res) * (1.0f / 64.0f);
    float c2 = res - m2;
    float var2 = waveSum(c2 * c2) * (1.0f / 64.0f);
    float qv = (c2 / sqrtf(var2 + 1e-8f)) * g1n[d] + b1n[d];
    qs[wid][d] = qv;
    xs[wid][d] = res;
    q[(size_t)row * DD + d] = qv;
    float aq = bq[d], ak = bk[d], av = bv[d];
#pragma unroll 8
    for (int j = 0; j < DD; ++j) {
        aq = fmaf(qs[wid][j], WqT[j * DD + d], aq);
        ak = fmaf(xs[wid][j], WkT[j * DD + d], ak);
        av = fmaf(xs[wid][j], WvT[j * DD + d], av);
    }
    Q[(size_t)row * DD + d] = aq;
    K[(size_t)row * DD + d] = ak + posK[l * DD + d];
    V[(size_t)row * DD + d] = av + posV[l * DD + d];
    Qsh[wid][d] = aq;
    __syncthreads();
    qt_tail(Qsh, tKT, Qt_g, blockIdx.x * 4);
}

// END: addln_ffn(last layer) fused with final LN + logits. 4 rows/block.
__global__ void end_kernel(const float* __restrict__ qin,
                           const float* __restrict__ att,
                           const float* __restrict__ g2, const float* __restrict__ b2ln,
                           const float* __restrict__ W1T, const float* __restrict__ b1v,
                           const float* __restrict__ W2T, const float* __restrict__ b2v,
                           const int* __restrict__ log_ids,
                           const float* __restrict__ lnf_g, const float* __restrict__ lnf_b,
                           const float* __restrict__ item_emb,
                           const int* __restrict__ pos_ids,
                           const int* __restrict__ neg_ids,
                           float* __restrict__ out) {
    __shared__ float xs[4][DD], hs[4][DD];
    int tid = threadIdx.x;
    int wid = tid >> 6, d = tid & 63;
    int row = blockIdx.x * 4 + wid;
    float v = qin[(size_t)row * DD + d] + att[(size_t)row * DD + d];
    float m = waveSum(v) * (1.0f / 64.0f);
    float c = v - m;
    float var = waveSum(c * c) * (1.0f / 64.0f);
    float xv = (c / sqrtf(var + 1e-8f)) * g2[d] + b2ln[d];
    xs[wid][d] = xv;
    float a = b1v[d];
#pragma unroll 8
    for (int j = 0; j < DD; ++j) a = fmaf(xs[wid][j], W1T[j * DD + d], a);
    hs[wid][d] = fmaxf(a, 0.0f);
    float o = b2v[d];
#pragma unroll 8
    for (int j = 0; j < DD; ++j) o = fmaf(hs[wid][j], W2T[j * DD + d], o);
    float res = xv + o;
    if (log_ids[row] == 0) res = 0.0f;
    // --- final LN + logits ---
    float m2 = waveSum(res) * (1.0f / 64.0f);
    float c2 = res - m2;
    float var2 = waveSum(c2 * c2) * (1.0f / 64.0f);
    float f = (c2 / sqrtf(var2 + 1e-8f)) * lnf_g[d] + lnf_b[d];
    int pid = pos_ids[row];
    int nid = neg_ids[row];
    float p = waveSum(f * item_emb[(size_t)pid * DD + d]);
    float n = waveSum(f * item_emb[(size_t)nid * DD + d]);
    if (d == 0) {
        out[row] = p;
        out[BB * LLEN + row] = n;
    }
}

extern "C" void kernel_launch(void* const* d_in, const int* in_sizes, int n_in,
                              void* d_out, int out_size, void* d_ws, size_t ws_size,
                              hipStream_t stream) {
    const int* log_ids = (const int*)d_in[0];
    const int* log_times = (const int*)d_in[1];
    const int* pos_ids = (const int*)d_in[2];
    const int* neg_ids = (const int*)d_in[3];
    const float* item_emb = (const float*)d_in[4];
    const float* posK = (const float*)d_in[5];
    const float* posV = (const float*)d_in[6];
    const float* tK_emb = (const float*)d_in[7];
    const float* tV_emb = (const float*)d_in[8];
    const float* ln1_g = (const float*)d_in[9];
    const float* ln1_b = (const float*)d_in[10];
    const float* Wq = (const float*)d_in[11];
    const float* bq = (const float*)d_in[12];
    const float* Wk = (const float*)d_in[13];
    const float* bk = (const float*)d_in[14];
    const float* Wv = (const float*)d_in[15];
    const float* bv = (const float*)d_in[16];
    const float* ln2_g = (const float*)d_in[17];
    const float* ln2_b = (const float*)d_in[18];
    const float* W1 = (const float*)d_in[19];
    const float* b1 = (const float*)d_in[20];
    const float* W2 = (const float*)d_in[21];
    const float* b2 = (const float*)d_in[22];
    const float* lnf_g = (const float*)d_in[23];
    const float* lnf_b = (const float*)d_in[24];

    float* ws = (float*)d_ws;
    float* q = ws;                        // ln1 output (residual)
    float* Qb = q + BLD;
    float* Kb = Qb + BLD;
    float* Vb = Kb + BLD;
    float* att = Vb + BLD;
    float* wt = att + BLD;                // 10 x 64x64 transposed weights
    float* tKT = wt + 10 * DD * DD;       // [64][366]
    unsigned short* Qt = (unsigned short*)(tKT + DD * TSPAN1);  // [6400][732] bf16

    const int nrow = BB * LLEN;           // 6400

    const float* W1T0 = wt + 3 * DD * DD;
    const float* W2T0 = wt + 4 * DD * DD;
    const float* W1T1 = wt + 8 * DD * DD;
    const float* W2T1 = wt + 9 * DD * DD;

    transpose_kernel<<<11, 256, 0, stream>>>(Wq, Wk, Wv, W1, W2, tK_emb, wt, tKT);

    // layer 0 entry (embed + qt fused)
    ln_qkv_kernel<<<nrow / 4, 256, 0, stream>>>(log_ids, item_emb,
                                                ln1_g, ln1_b,
                                                wt + 0 * DD * DD, bq,
                                                wt + 1 * DD * DD, bk,
                                                wt + 2 * DD * DD, bv,
                                                posK, posV, tKT,
                                                q, Qb, Kb, Vb, Qt);
    attn_kernel<<<BB * 50, 256, 0, stream>>>(Qb, Kb, Vb, log_times, Qt, tV_emb, att);

    // layer 0 tail + layer 1 entry (+ qt fused)
    mid_kernel<<<nrow / 4, 256, 0, stream>>>(q, att,
                                             ln2_g, ln2_b,
                                             W1T0, b1, W2T0, b2,
                                             log_ids,
                                             ln1_g + DD, ln1_b + DD,
                                             wt + 5 * DD * DD, bq + DD,
                                             wt + 6 * DD * DD, bk + DD,
                                             wt + 7 * DD * DD, bv + DD,
                                             posK, posV, tKT,
                                             q, Qb, Kb, Vb, Qt);
    attn_kernel<<<BB * 50, 256, 0, stream>>>(Qb, Kb, Vb, log_times, Qt, tV_emb, att);

    // layer 1 tail + final logits
    end_kernel<<<nrow / 4, 256, 0, stream>>>(q, att,
                                             ln2_g + DD, ln2_b + DD,
                                             W1T1, b1 + DD, W2T1, b2 + DD,
                                             log_ids,
                                             lnf_g, lnf_b, item_emb,
                                             pos_ids, neg_ids, (float*)d_out);
}